// Round 13
// baseline (183.751 us; speedup 1.0000x reference)
//
#include <hip/hip_runtime.h>

#define NEWL 150
#define EMBD 64
#define NCOL 256
#define CIMU 48
#define CEMG 16

#define KIMU (NEWL * CIMU)  // 7200
#define KEMG (NEWL * CEMG)  // 2400
#define KSTI 225            // total k-steps (32-wide) imu
#define KSTE 75             // total k-steps emg
#define NCI 4               // imu s-chunks (19/19/19/18 groups)
#define NCE 2               // emg s-chunks (13/12 groups)

typedef __bf16 bf16x8_t __attribute__((ext_vector_type(8)));
typedef __bf16 bf16x4_t __attribute__((ext_vector_type(4)));
typedef float f32x4_t __attribute__((ext_vector_type(4)));

__device__ __forceinline__ f32x4_t mfma16(bf16x8_t a, bf16x8_t b, f32x4_t c) {
  return __builtin_amdgcn_mfma_f32_16x16x32_bf16(a, b, c, 0, 0, 0);
}

// ---------- K0: combined weights packed in MFMA B-fragment order + bias partials.
// W_pack[cb][ks][lane=h*16+(col&15)][u]  where k = ks*32 + h*8 + u
template <int C, int KST>
__device__ void wcomb_body(const float* __restrict__ wemb,
                           const float* __restrict__ wreg_src,
                           __bf16* __restrict__ wpk, int s, int j) {
  float wreg[EMBD];
#pragma unroll
  for (int e = 0; e < EMBD; ++e) wreg[e] = wreg_src[(size_t)e * NCOL];
  const int cb = j >> 4, lr = j & 15;
#pragma unroll
  for (int q = 0; q < C / 8; ++q) {
    const int kq = (s * C) / 8 + q;
    const int ks = kq >> 2, h = kq & 3;
    bf16x8_t tv;
#pragma unroll
    for (int u = 0; u < 8; ++u) {
      const float* we = wemb + (q * 8 + u) * EMBD;
      float acc = 0.f;
#pragma unroll
      for (int e = 0; e < EMBD; ++e) acc = fmaf(we[e], wreg[e], acc);
      tv[u] = (__bf16)acc;
    }
    *(bf16x8_t*)(wpk + (((size_t)cb * KST + ks) * 64 + h * 16 + lr) * 8) = tv;
  }
}

__global__ __launch_bounds__(256) void wcomb_kernel(
    const float* __restrict__ w_emb_imu, const float* __restrict__ w_emb_emg,
    const float* __restrict__ b_emb_imu, const float* __restrict__ b_emb_emg,
    const float* __restrict__ w_proj,
    __bf16* __restrict__ wpk_imu, __bf16* __restrict__ wpk_emg,
    float* __restrict__ bpart) {
  const int s = blockIdx.x;   // 0..149
  const int m = blockIdx.y;   // 0 = imu, 1 = emg
  const int j = threadIdx.x;  // output column 0..255
  const float* wp_base = w_proj + (size_t)s * EMBD * NCOL + j;
  const float* be = (m == 0) ? b_emb_imu : b_emb_emg;
  float bacc = 0.f;
#pragma unroll
  for (int e = 0; e < EMBD; ++e) bacc = fmaf(be[e], wp_base[(size_t)e * NCOL], bacc);
  bpart[((size_t)m * NEWL + s) * NCOL + j] = bacc;
  if (m == 0)
    wcomb_body<CIMU, KSTI>(w_emb_imu, wp_base, wpk_imu, s, j);
  else
    wcomb_body<CEMG, KSTE>(w_emb_emg, wp_base, wpk_emg, s, j);
}

// ---------- K1: fused ragged-interp + MFMA GEMM (+ bias-reduce tail block)
// imu: distance-2 gather (two 24-float slots in gr[48]); emg: distance-1
// (gr[0..31], branch-exclusive so the allocator aliases). 128-VGPR clamp.
__global__ __launch_bounds__(256, 4) void fused_kernel(
    const float* __restrict__ x_imu, const float* __restrict__ x_emg,
    const int* __restrict__ lens,
    const __bf16* __restrict__ wpk_imu, const __bf16* __restrict__ wpk_emg,
    const float* __restrict__ b_proj, const float* __restrict__ bpart,
    float* __restrict__ p_imu, float* __restrict__ p_emg,
    float* __restrict__ bias, int B, int T) {
  const int bid = blockIdx.x;
  const int span = B >> 4;  // blocks per chunk (mtiles*2)
  const int mts = B >> 5;   // 32-row m-tiles
  if (bid == (NCE + NCI) * span) {  // bias tail block
    const int j = threadIdx.x;
#pragma unroll
    for (int m = 0; m < 2; ++m) {
      float acc = b_proj[j];
      for (int s = 0; s < NEWL; ++s) acc += bpart[((size_t)m * NEWL + s) * NCOL + j];
      bias[m * NCOL + j] = acc;
    }
    return;
  }

  __shared__ __bf16 lds[2][2][3][512];  // [buf][row-plane][ks][lane*8]

  const int tid = threadIdx.x;
  const int wv = tid >> 6, l = tid & 63;

  const int cs = bid / span;
  const int r = bid - cs * span;
  const bool is_imu = cs >= NCE;
  const int c = is_imu ? cs - NCE : cs;
  const int nh = r / mts, mt = r - nh * mts;

  // chunk geometry (group = 3 ksteps; imu: 2 s/group, emg: 6 s/group)
  int g0, NG;
  if (is_imu) { g0 = 19 * c; NG = (c < 3) ? 19 : 18; }
  else        { g0 = 13 * c; NG = c ? 12 : 13; }
  const int ks0 = 3 * g0;
  const int sb = is_imu ? 2 * g0 : 6 * g0;

  const __bf16* Wp = is_imu ? wpk_imu : wpk_emg;
  const int KST = is_imu ? KSTI : KSTE;
  float* P = is_imu ? (p_imu + (size_t)c * B * NCOL) : (p_emg + (size_t)c * B * NCOL);

  const size_t PS = (size_t)KST * 512;  // B fragment-plane stride (bf16)
  const __bf16* bg = Wp + ((size_t)(nh * 8 + wv * 2) * KST + ks0) * 512 + l * 8;

  // gather thread mappings
  const int q = tid & 3, sl = (tid >> 2) & 1, bli = tid >> 3;  // imu: 4 thr/(b,s)
  const int ble = tid / 6, se = tid - ble * 6;                 // emg: 1 thr/(b,s), tid<192
  const bool act = is_imu || (tid < 192);
  const int b_g = mt * 32 + (is_imu ? bli : (act ? ble : 0));
  int lenv = 1;
  float scale = 0.f;
  if (act) { lenv = lens[b_g]; scale = (float)lenv * (1.0f / 150.0f); }

  float gr[48];     // imu: 2 slots x 24; emg: distance-1 in gr[0..31]
  float wS[2];      // lerp weight per slot (emg uses wS[0])
  bf16x8_t bB[6];   // single B slot (2 planes x 3 ksteps)
  f32x4_t acc00 = {0.f, 0.f, 0.f, 0.f}, acc01 = acc00, acc10 = acc00, acc11 = acc00;

// imu gather, quad-contiguous, slot S (24 floats at gr[S*24]).
#define ISSUE_GI(g2, S) do {                                                    \
    const int s_ = sb + (g2) * 2 + sl;                                          \
    float src_ = fmaxf(((float)s_ + 0.5f) * scale - 0.5f, 0.0f);                \
    int i0_ = min((int)src_, lenv - 1);                                         \
    int i1_ = min(i0_ + 1, lenv - 1);                                           \
    wS[S] = src_ - (float)i0_;                                                  \
    const float* r0_ = x_imu + ((size_t)b_g * T + i0_) * CIMU + q * 4;          \
    const float* r1_ = x_imu + ((size_t)b_g * T + i1_) * CIMU + q * 4;          \
    _Pragma("unroll")                                                           \
    for (int t = 0; t < 3; ++t) {                                               \
      float4 v_ = *(const float4*)(r0_ + t * 16);                               \
      gr[(S) * 24 + t * 4 + 0] = v_.x; gr[(S) * 24 + t * 4 + 1] = v_.y;         \
      gr[(S) * 24 + t * 4 + 2] = v_.z; gr[(S) * 24 + t * 4 + 3] = v_.w;         \
      float4 u_ = *(const float4*)(r1_ + t * 16);                               \
      gr[(S) * 24 + 12 + t * 4 + 0] = u_.x; gr[(S) * 24 + 12 + t * 4 + 1] = u_.y;\
      gr[(S) * 24 + 12 + t * 4 + 2] = u_.z; gr[(S) * 24 + 12 + t * 4 + 3] = u_.w;\
    }                                                                           \
  } while (0)

// in-lane lerp from slot S; all 4 quad threads write distinct bf16x4 pieces.
#define LERP_WI(S, BUF) do {                                                    \
    const float wg_ = wS[S], om_ = 1.0f - wg_;                                  \
    _Pragma("unroll")                                                           \
    for (int t = 0; t < 3; ++t) {                                               \
      bf16x4_t o_;                                                              \
      _Pragma("unroll")                                                         \
      for (int u = 0; u < 4; ++u)                                               \
        o_[u] = (__bf16)(gr[(S) * 24 + t * 4 + u] * om_ +                       \
                         gr[(S) * 24 + 12 + t * 4 + u] * wg_);                  \
      const int kq_ = sl * 6 + t * 2 + (q >> 1);                                \
      *(bf16x4_t*)(&lds[BUF][bli >> 4][kq_ >> 2]                                \
                       [((kq_ & 3) * 16 + (bli & 15)) * 8 + (q & 1) * 4]) = o_; \
    }                                                                           \
  } while (0)

#define ISSUE_GE(g2) do { if (act) {                                            \
    const int s_ = sb + (g2) * 6 + se;                                          \
    float src_ = fmaxf(((float)s_ + 0.5f) * scale - 0.5f, 0.0f);                \
    int i0_ = min((int)src_, lenv - 1);                                         \
    int i1_ = min(i0_ + 1, lenv - 1);                                           \
    wS[0] = src_ - (float)i0_;                                                  \
    const float* p0_ = x_emg + ((size_t)b_g * T + i0_) * CEMG;                  \
    const float* p1_ = x_emg + ((size_t)b_g * T + i1_) * CEMG;                  \
    _Pragma("unroll")                                                           \
    for (int t = 0; t < 4; ++t) {                                               \
      float4 v_ = *(const float4*)(p0_ + t * 4);                                \
      gr[t * 4 + 0] = v_.x; gr[t * 4 + 1] = v_.y;                               \
      gr[t * 4 + 2] = v_.z; gr[t * 4 + 3] = v_.w;                               \
      float4 u_ = *(const float4*)(p1_ + t * 4);                                \
      gr[16 + t * 4 + 0] = u_.x; gr[16 + t * 4 + 1] = u_.y;                     \
      gr[16 + t * 4 + 2] = u_.z; gr[16 + t * 4 + 3] = u_.w;                     \
    }                                                                           \
  } } while (0)

#define LERP_WE(BUF) do { if (act) {                                            \
    const float wg_ = wS[0], om_ = 1.0f - wg_;                                  \
    _Pragma("unroll")                                                           \
    for (int t2 = 0; t2 < 2; ++t2) {                                            \
      bf16x8_t o_;                                                              \
      _Pragma("unroll")                                                         \
      for (int u = 0; u < 8; ++u)                                               \
        o_[u] = (__bf16)(gr[t2 * 8 + u] * om_ + gr[16 + t2 * 8 + u] * wg_);     \
      const int kq_ = se * 2 + t2;                                              \
      *(bf16x8_t*)(&lds[BUF][ble >> 4][kq_ >> 2]                                \
                       [((kq_ & 3) * 16 + (ble & 15)) * 8]) = o_;               \
    }                                                                           \
  } } while (0)

#define ISSUE_B(g1) do {                                                        \
    const __bf16* pb_ = bg + (size_t)((g1) * 3) * 512;                          \
    _Pragma("unroll")                                                           \
    for (int ks = 0; ks < 3; ++ks) {                                            \
      bB[ks * 2 + 0] = *(const bf16x8_t*)(pb_ + (size_t)ks * 512);              \
      bB[ks * 2 + 1] = *(const bf16x8_t*)(pb_ + PS + (size_t)ks * 512);         \
    }                                                                           \
  } while (0)

#define COMPUTE(Pp) do {                                                        \
    _Pragma("unroll")                                                           \
    for (int ks = 0; ks < 3; ++ks) {                                            \
      bf16x8_t a0_ = *(const bf16x8_t*)(&lds[Pp][0][ks][l * 8]);                \
      bf16x8_t a1_ = *(const bf16x8_t*)(&lds[Pp][1][ks][l * 8]);                \
      acc00 = mfma16(a0_, bB[ks * 2 + 0], acc00);                               \
      acc01 = mfma16(a0_, bB[ks * 2 + 1], acc01);                               \
      acc10 = mfma16(a1_, bB[ks * 2 + 0], acc10);                               \
      acc11 = mfma16(a1_, bB[ks * 2 + 1], acc11);                               \
    }                                                                           \
  } while (0)

  if (is_imu) {
    // prologue: groups 0,1 in flight; group 0 staged; B0 loaded
    ISSUE_GI(0, 0);
    ISSUE_GI(1, 1);
    LERP_WI(0, 0);
    ISSUE_B(0);
    __syncthreads();
    for (int p = 0; p < NG; ++p) {
      if (p + 2 < NG) ISSUE_GI(p + 2, p & 1);   // slot p&1 freed last phase
      COMPUTE(p & 1);
      if (p + 1 < NG) ISSUE_B(p + 1);
      if (p + 1 < NG) LERP_WI((p + 1) & 1, (p + 1) & 1);
      __syncthreads();
    }
  } else {
    // emg: distance-1 single slot (13 phases max — has slack vs imu's 19)
    ISSUE_GE(0);
    LERP_WE(0);
    ISSUE_B(0);
    __syncthreads();
    for (int p = 0; p < NG; ++p) {
      const int more = (p + 1 < NG);
      if (more) ISSUE_GE(p + 1);
      COMPUTE(p & 1);
      if (more) ISSUE_B(p + 1);
      if (more) LERP_WE((p + 1) & 1);
      __syncthreads();
    }
  }

  // epilogue: C/D col = lane&15, row = (lane>>4)*4 + reg
  const int lh = l >> 4, lr = l & 15;
  float* Pb = P + (size_t)(mt * 32 + lh * 4) * NCOL + nh * 128 + wv * 32 + lr;
#pragma unroll
  for (int jj = 0; jj < 4; ++jj) {
    Pb[(size_t)jj * NCOL] = acc00[jj];
    Pb[(size_t)jj * NCOL + 16] = acc01[jj];
    Pb[(size_t)(16 + jj) * NCOL] = acc10[jj];
    Pb[(size_t)(16 + jj) * NCOL + 16] = acc11[jj];
  }
#undef ISSUE_GI
#undef LERP_WI
#undef ISSUE_GE
#undef LERP_WE
#undef ISSUE_B
#undef COMPUTE
}

// ---------- K2: sum split-K partials + bias -> d_out
__global__ __launch_bounds__(256) void combine_kernel(
    const float* __restrict__ bias, const float* __restrict__ p_imu,
    const float* __restrict__ p_emg, float* __restrict__ out, int B) {
  const int b = blockIdx.x, m = blockIdx.y, j = threadIdx.x;
  const size_t n = (size_t)B * NCOL;
  const size_t o = (size_t)b * NCOL + j;
  if (m == 0) {
    float v = bias[j];
#pragma unroll
    for (int c = 0; c < NCI; ++c) v += p_imu[c * n + o];
    out[o] = v;
  } else {
    out[n + o] = bias[NCOL + j] + p_emg[o] + p_emg[n + o];
  }
}

extern "C" void kernel_launch(void* const* d_in, const int* in_sizes, int n_in,
                              void* d_out, int out_size, void* d_ws, size_t ws_size,
                              hipStream_t stream) {
  const float* x_imu     = (const float*)d_in[0];
  const float* x_emg     = (const float*)d_in[1];
  const int*   lens      = (const int*)d_in[2];
  const float* w_emb_imu = (const float*)d_in[3];
  const float* b_emb_imu = (const float*)d_in[4];
  const float* w_emb_emg = (const float*)d_in[5];
  const float* b_emb_emg = (const float*)d_in[6];
  const float* w_proj    = (const float*)d_in[7];
  const float* b_proj    = (const float*)d_in[8];
  float* out = (float*)d_out;

  const int B = in_sizes[2];
  const int T = in_sizes[0] / (B * CIMU);

  char* ws = (char*)d_ws;
  __bf16* wpk_imu = (__bf16*)ws;  ws += (size_t)NCOL * KIMU * 2;
  __bf16* wpk_emg = (__bf16*)ws;  ws += (size_t)NCOL * KEMG * 2;
  float*  bias    = (float*)ws;   ws += 2 * NCOL * 4;
  float*  bpart   = (float*)ws;   ws += (size_t)2 * NEWL * NCOL * 4;
  float*  p_imu   = (float*)ws;   ws += (size_t)NCI * B * NCOL * 4;
  float*  p_emg   = (float*)ws;   ws += (size_t)NCE * B * NCOL * 4;

  wcomb_kernel<<<dim3(NEWL, 2), 256, 0, stream>>>(
      w_emb_imu, w_emb_emg, b_emb_imu, b_emb_emg, w_proj, wpk_imu, wpk_emg, bpart);
  const int span = B >> 4;                        // 128
  const int nblk = (NCE + NCI) * span + 1;        // 769
  fused_kernel<<<nblk, 256, 0, stream>>>(x_imu, x_emg, lens, wpk_imu, wpk_emg,
                                         b_proj, bpart, p_imu, p_emg, bias, B, T);
  combine_kernel<<<dim3(B, 2), 256, 0, stream>>>(bias, p_imu, p_emg, out, B);
}

// Round 14
// 82.990 us; speedup vs baseline: 2.2141x; 2.2141x over previous
//
#include <hip/hip_runtime.h>

#define NEWL 150
#define EMBD 64
#define NCOL 256
#define CIMU 48
#define CEMG 16

#define KIMU (NEWL * CIMU)  // 7200
#define KEMG (NEWL * CEMG)  // 2400
#define KSTI 225            // total k-steps (32-wide) imu
#define KSTE 75             // total k-steps emg
#define NCI 4               // imu s-chunks (19/19/19/18 groups)
#define NCE 2               // emg s-chunks (13/12 groups)

typedef __bf16 bf16x8_t __attribute__((ext_vector_type(8)));
typedef __bf16 bf16x4_t __attribute__((ext_vector_type(4)));
typedef float f32x4_t __attribute__((ext_vector_type(4)));

__device__ __forceinline__ f32x4_t mfma16(bf16x8_t a, bf16x8_t b, f32x4_t c) {
  return __builtin_amdgcn_mfma_f32_16x16x32_bf16(a, b, c, 0, 0, 0);
}

// ---------- K0: combined weights packed in MFMA B-fragment order + bias partials.
// W_pack[cb][ks][lane=h*16+(col&15)][u]  where k = ks*32 + h*8 + u
template <int C, int KST>
__device__ void wcomb_body(const float* __restrict__ wemb,
                           const float* __restrict__ wreg_src,
                           __bf16* __restrict__ wpk, int s, int j) {
  float wreg[EMBD];
#pragma unroll
  for (int e = 0; e < EMBD; ++e) wreg[e] = wreg_src[(size_t)e * NCOL];
  const int cb = j >> 4, lr = j & 15;
#pragma unroll
  for (int q = 0; q < C / 8; ++q) {
    const int kq = (s * C) / 8 + q;
    const int ks = kq >> 2, h = kq & 3;
    bf16x8_t tv;
#pragma unroll
    for (int u = 0; u < 8; ++u) {
      const float* we = wemb + (q * 8 + u) * EMBD;
      float acc = 0.f;
#pragma unroll
      for (int e = 0; e < EMBD; ++e) acc = fmaf(we[e], wreg[e], acc);
      tv[u] = (__bf16)acc;
    }
    *(bf16x8_t*)(wpk + (((size_t)cb * KST + ks) * 64 + h * 16 + lr) * 8) = tv;
  }
}

__global__ __launch_bounds__(256) void wcomb_kernel(
    const float* __restrict__ w_emb_imu, const float* __restrict__ w_emb_emg,
    const float* __restrict__ b_emb_imu, const float* __restrict__ b_emb_emg,
    const float* __restrict__ w_proj,
    __bf16* __restrict__ wpk_imu, __bf16* __restrict__ wpk_emg,
    float* __restrict__ bpart) {
  const int s = blockIdx.x;   // 0..149
  const int m = blockIdx.y;   // 0 = imu, 1 = emg
  const int j = threadIdx.x;  // output column 0..255
  const float* wp_base = w_proj + (size_t)s * EMBD * NCOL + j;
  const float* be = (m == 0) ? b_emb_imu : b_emb_emg;
  float bacc = 0.f;
#pragma unroll
  for (int e = 0; e < EMBD; ++e) bacc = fmaf(be[e], wp_base[(size_t)e * NCOL], bacc);
  bpart[((size_t)m * NEWL + s) * NCOL + j] = bacc;
  if (m == 0)
    wcomb_body<CIMU, KSTI>(w_emb_imu, wp_base, wpk_imu, s, j);
  else
    wcomb_body<CEMG, KSTE>(w_emb_emg, wp_base, wpk_emg, s, j);
}

// ---------- K1: fused ragged-interp + MFMA GEMM (+ bias-reduce tail block)
// imu: distance-2 gather, two 24-float slots with STATIC indices (rule #20:
// runtime-indexed register arrays spill to scratch — R13's 183µs lesson).
// emg: distance-1. 128-VGPR clamp for 4 blocks/CU.
__global__ __launch_bounds__(256, 4) void fused_kernel(
    const float* __restrict__ x_imu, const float* __restrict__ x_emg,
    const int* __restrict__ lens,
    const __bf16* __restrict__ wpk_imu, const __bf16* __restrict__ wpk_emg,
    const float* __restrict__ b_proj, const float* __restrict__ bpart,
    float* __restrict__ p_imu, float* __restrict__ p_emg,
    float* __restrict__ bias, int B, int T) {
  const int bid = blockIdx.x;
  const int span = B >> 4;  // blocks per chunk (mtiles*2)
  const int mts = B >> 5;   // 32-row m-tiles
  if (bid == (NCE + NCI) * span) {  // bias tail block
    const int j = threadIdx.x;
#pragma unroll
    for (int m = 0; m < 2; ++m) {
      float acc = b_proj[j];
      for (int s = 0; s < NEWL; ++s) acc += bpart[((size_t)m * NEWL + s) * NCOL + j];
      bias[m * NCOL + j] = acc;
    }
    return;
  }

  __shared__ __bf16 lds[2][2][3][512];  // [buf][row-plane][ks][lane*8]

  const int tid = threadIdx.x;
  const int wv = tid >> 6, l = tid & 63;

  const int cs = bid / span;
  const int r = bid - cs * span;
  const bool is_imu = cs >= NCE;
  const int c = is_imu ? cs - NCE : cs;
  const int nh = r / mts, mt = r - nh * mts;

  // chunk geometry (group = 3 ksteps; imu: 2 s/group, emg: 6 s/group)
  int g0, NG;
  if (is_imu) { g0 = 19 * c; NG = (c < 3) ? 19 : 18; }
  else        { g0 = 13 * c; NG = c ? 12 : 13; }
  const int ks0 = 3 * g0;
  const int sb = is_imu ? 2 * g0 : 6 * g0;

  const __bf16* Wp = is_imu ? wpk_imu : wpk_emg;
  const int KST = is_imu ? KSTI : KSTE;
  float* P = is_imu ? (p_imu + (size_t)c * B * NCOL) : (p_emg + (size_t)c * B * NCOL);

  const size_t PS = (size_t)KST * 512;  // B fragment-plane stride (bf16)
  const __bf16* bg = Wp + ((size_t)(nh * 8 + wv * 2) * KST + ks0) * 512 + l * 8;

  // gather thread mappings
  const int q = tid & 3, sl = (tid >> 2) & 1, bli = tid >> 3;  // imu: 4 thr/(b,s)
  const int ble = tid / 6, se = tid - ble * 6;                 // emg: 1 thr/(b,s), tid<192
  const bool act = is_imu || (tid < 192);
  const int b_g = mt * 32 + (is_imu ? bli : (act ? ble : 0));
  int lenv = 1;
  float scale = 0.f;
  if (act) { lenv = lens[b_g]; scale = (float)lenv * (1.0f / 150.0f); }

  float gr0[24], gr1[24];  // imu: two STATIC slots; emg uses gr0+gr1[0..7]
  float wS0, wS1;          // lerp weight per slot
  bf16x8_t bB[6];          // single B slot (2 planes x 3 ksteps)
  f32x4_t acc00 = {0.f, 0.f, 0.f, 0.f}, acc01 = acc00, acc10 = acc00, acc11 = acc00;

// imu gather, quad-contiguous, into STATIC slot GRS (gr0 or gr1).
#define ISSUE_GI(g2, GRS, WSV) do {                                             \
    const int s_ = sb + (g2) * 2 + sl;                                          \
    float src_ = fmaxf(((float)s_ + 0.5f) * scale - 0.5f, 0.0f);                \
    int i0_ = min((int)src_, lenv - 1);                                         \
    int i1_ = min(i0_ + 1, lenv - 1);                                           \
    WSV = src_ - (float)i0_;                                                    \
    const float* r0_ = x_imu + ((size_t)b_g * T + i0_) * CIMU + q * 4;          \
    const float* r1_ = x_imu + ((size_t)b_g * T + i1_) * CIMU + q * 4;          \
    _Pragma("unroll")                                                           \
    for (int t = 0; t < 3; ++t) {                                               \
      float4 v_ = *(const float4*)(r0_ + t * 16);                               \
      GRS[t * 4 + 0] = v_.x; GRS[t * 4 + 1] = v_.y;                             \
      GRS[t * 4 + 2] = v_.z; GRS[t * 4 + 3] = v_.w;                             \
      float4 u_ = *(const float4*)(r1_ + t * 16);                               \
      GRS[12 + t * 4 + 0] = u_.x; GRS[12 + t * 4 + 1] = u_.y;                   \
      GRS[12 + t * 4 + 2] = u_.z; GRS[12 + t * 4 + 3] = u_.w;                   \
    }                                                                           \
  } while (0)

// in-lane lerp from STATIC slot; all 4 quad threads write distinct pieces.
#define LERP_WI(GRS, WSV, BUF) do {                                             \
    const float wg_ = WSV, om_ = 1.0f - wg_;                                    \
    _Pragma("unroll")                                                           \
    for (int t = 0; t < 3; ++t) {                                               \
      bf16x4_t o_;                                                              \
      _Pragma("unroll")                                                         \
      for (int u = 0; u < 4; ++u)                                               \
        o_[u] = (__bf16)(GRS[t * 4 + u] * om_ + GRS[12 + t * 4 + u] * wg_);     \
      const int kq_ = sl * 6 + t * 2 + (q >> 1);                                \
      *(bf16x4_t*)(&lds[BUF][bli >> 4][kq_ >> 2]                                \
                       [((kq_ & 3) * 16 + (bli & 15)) * 8 + (q & 1) * 4]) = o_; \
    }                                                                           \
  } while (0)

// emg gather (distance-1): rows i0 -> gr0[0..15], i1 -> gr0[16..23]+gr1[0..7]
#define ISSUE_GE(g2) do { if (act) {                                            \
    const int s_ = sb + (g2) * 6 + se;                                          \
    float src_ = fmaxf(((float)s_ + 0.5f) * scale - 0.5f, 0.0f);                \
    int i0_ = min((int)src_, lenv - 1);                                         \
    int i1_ = min(i0_ + 1, lenv - 1);                                           \
    wS0 = src_ - (float)i0_;                                                    \
    const float* p0_ = x_emg + ((size_t)b_g * T + i0_) * CEMG;                  \
    const float* p1_ = x_emg + ((size_t)b_g * T + i1_) * CEMG;                  \
    _Pragma("unroll")                                                           \
    for (int t = 0; t < 4; ++t) {                                               \
      float4 v_ = *(const float4*)(p0_ + t * 4);                                \
      gr0[t * 4 + 0] = v_.x; gr0[t * 4 + 1] = v_.y;                             \
      gr0[t * 4 + 2] = v_.z; gr0[t * 4 + 3] = v_.w;                             \
    }                                                                           \
    _Pragma("unroll")                                                           \
    for (int t = 0; t < 2; ++t) {                                               \
      float4 v_ = *(const float4*)(p1_ + t * 4);                                \
      gr0[16 + t * 4 + 0] = v_.x; gr0[16 + t * 4 + 1] = v_.y;                   \
      gr0[16 + t * 4 + 2] = v_.z; gr0[16 + t * 4 + 3] = v_.w;                   \
    }                                                                           \
    _Pragma("unroll")                                                           \
    for (int t = 0; t < 2; ++t) {                                               \
      float4 v_ = *(const float4*)(p1_ + 8 + t * 4);                            \
      gr1[t * 4 + 0] = v_.x; gr1[t * 4 + 1] = v_.y;                             \
      gr1[t * 4 + 2] = v_.z; gr1[t * 4 + 3] = v_.w;                             \
    }                                                                           \
  } } while (0)

#define LERP_WE(BUF) do { if (act) {                                            \
    const float wg_ = wS0, om_ = 1.0f - wg_;                                    \
    bf16x8_t o_;                                                                \
    _Pragma("unroll")                                                           \
    for (int u = 0; u < 8; ++u)                                                 \
      o_[u] = (__bf16)(gr0[u] * om_ + gr0[16 + u] * wg_);                       \
    const int kq0_ = se * 2;                                                    \
    *(bf16x8_t*)(&lds[BUF][ble >> 4][kq0_ >> 2]                                 \
                     [((kq0_ & 3) * 16 + (ble & 15)) * 8]) = o_;                \
    _Pragma("unroll")                                                           \
    for (int u = 0; u < 8; ++u)                                                 \
      o_[u] = (__bf16)(gr0[8 + u] * om_ + gr1[u] * wg_);                        \
    const int kq1_ = se * 2 + 1;                                                \
    *(bf16x8_t*)(&lds[BUF][ble >> 4][kq1_ >> 2]                                 \
                     [((kq1_ & 3) * 16 + (ble & 15)) * 8]) = o_;                \
  } } while (0)

#define ISSUE_B(g1) do {                                                        \
    const __bf16* pb_ = bg + (size_t)((g1) * 3) * 512;                          \
    _Pragma("unroll")                                                           \
    for (int ks = 0; ks < 3; ++ks) {                                            \
      bB[ks * 2 + 0] = *(const bf16x8_t*)(pb_ + (size_t)ks * 512);              \
      bB[ks * 2 + 1] = *(const bf16x8_t*)(pb_ + PS + (size_t)ks * 512);         \
    }                                                                           \
  } while (0)

#define COMPUTE(Pp) do {                                                        \
    _Pragma("unroll")                                                           \
    for (int ks = 0; ks < 3; ++ks) {                                            \
      bf16x8_t a0_ = *(const bf16x8_t*)(&lds[Pp][0][ks][l * 8]);                \
      bf16x8_t a1_ = *(const bf16x8_t*)(&lds[Pp][1][ks][l * 8]);                \
      acc00 = mfma16(a0_, bB[ks * 2 + 0], acc00);                               \
      acc01 = mfma16(a0_, bB[ks * 2 + 1], acc01);                               \
      acc10 = mfma16(a1_, bB[ks * 2 + 0], acc10);                               \
      acc11 = mfma16(a1_, bB[ks * 2 + 1], acc11);                               \
    }                                                                           \
  } while (0)

  if (is_imu) {
    // prologue: groups 0,1 in flight; group 0 staged in buf0; B0 loaded
    ISSUE_GI(0, gr0, wS0);
    ISSUE_GI(1, gr1, wS1);
    LERP_WI(gr0, wS0, 0);
    ISSUE_B(0);
    __syncthreads();
    for (int gp = 0; gp < (19 + 1) / 2; ++gp) {
      const int g = gp * 2;
      if (g >= NG) break;
      {
        if (g + 2 < NG) ISSUE_GI(g + 2, gr0, wS0);  // slot0 freed at prev LERP
        COMPUTE(0);
        if (g + 1 < NG) ISSUE_B(g + 1);
        if (g + 1 < NG) LERP_WI(gr1, wS1, 1);
        __syncthreads();
      }
      if (g + 1 < NG) {
        if (g + 3 < NG) ISSUE_GI(g + 3, gr1, wS1);
        COMPUTE(1);
        if (g + 2 < NG) ISSUE_B(g + 2);
        if (g + 2 < NG) LERP_WI(gr0, wS0, 0);
        __syncthreads();
      }
    }
  } else {
    // emg: distance-1 single slot (13 phases max — slack vs imu's 19)
    ISSUE_GE(0);
    LERP_WE(0);
    ISSUE_B(0);
    __syncthreads();
    for (int gp = 0; gp < (13 + 1) / 2; ++gp) {
      const int g = gp * 2;
      if (g >= NG) break;
      {
        if (g + 1 < NG) ISSUE_GE(g + 1);
        COMPUTE(0);
        if (g + 1 < NG) ISSUE_B(g + 1);
        if (g + 1 < NG) LERP_WE(1);
        __syncthreads();
      }
      if (g + 1 < NG) {
        if (g + 2 < NG) ISSUE_GE(g + 2);
        COMPUTE(1);
        if (g + 2 < NG) ISSUE_B(g + 2);
        if (g + 2 < NG) LERP_WE(0);
        __syncthreads();
      }
    }
  }

  // epilogue: C/D col = lane&15, row = (lane>>4)*4 + reg
  const int lh = l >> 4, lr = l & 15;
  float* Pb = P + (size_t)(mt * 32 + lh * 4) * NCOL + nh * 128 + wv * 32 + lr;
#pragma unroll
  for (int jj = 0; jj < 4; ++jj) {
    Pb[(size_t)jj * NCOL] = acc00[jj];
    Pb[(size_t)jj * NCOL + 16] = acc01[jj];
    Pb[(size_t)(16 + jj) * NCOL] = acc10[jj];
    Pb[(size_t)(16 + jj) * NCOL + 16] = acc11[jj];
  }
#undef ISSUE_GI
#undef LERP_WI
#undef ISSUE_GE
#undef LERP_WE
#undef ISSUE_B
#undef COMPUTE
}

// ---------- K2: sum split-K partials + bias -> d_out
__global__ __launch_bounds__(256) void combine_kernel(
    const float* __restrict__ bias, const float* __restrict__ p_imu,
    const float* __restrict__ p_emg, float* __restrict__ out, int B) {
  const int b = blockIdx.x, m = blockIdx.y, j = threadIdx.x;
  const size_t n = (size_t)B * NCOL;
  const size_t o = (size_t)b * NCOL + j;
  if (m == 0) {
    float v = bias[j];
#pragma unroll
    for (int c = 0; c < NCI; ++c) v += p_imu[c * n + o];
    out[o] = v;
  } else {
    out[n + o] = bias[NCOL + j] + p_emg[o] + p_emg[n + o];
  }
}

extern "C" void kernel_launch(void* const* d_in, const int* in_sizes, int n_in,
                              void* d_out, int out_size, void* d_ws, size_t ws_size,
                              hipStream_t stream) {
  const float* x_imu     = (const float*)d_in[0];
  const float* x_emg     = (const float*)d_in[1];
  const int*   lens      = (const int*)d_in[2];
  const float* w_emb_imu = (const float*)d_in[3];
  const float* b_emb_imu = (const float*)d_in[4];
  const float* w_emb_emg = (const float*)d_in[5];
  const float* b_emb_emg = (const float*)d_in[6];
  const float* w_proj    = (const float*)d_in[7];
  const float* b_proj    = (const float*)d_in[8];
  float* out = (float*)d_out;

  const int B = in_sizes[2];
  const int T = in_sizes[0] / (B * CIMU);

  char* ws = (char*)d_ws;
  __bf16* wpk_imu = (__bf16*)ws;  ws += (size_t)NCOL * KIMU * 2;
  __bf16* wpk_emg = (__bf16*)ws;  ws += (size_t)NCOL * KEMG * 2;
  float*  bias    = (float*)ws;   ws += 2 * NCOL * 4;
  float*  bpart   = (float*)ws;   ws += (size_t)2 * NEWL * NCOL * 4;
  float*  p_imu   = (float*)ws;   ws += (size_t)NCI * B * NCOL * 4;
  float*  p_emg   = (float*)ws;   ws += (size_t)NCE * B * NCOL * 4;

  wcomb_kernel<<<dim3(NEWL, 2), 256, 0, stream>>>(
      w_emb_imu, w_emb_emg, b_emb_imu, b_emb_emg, w_proj, wpk_imu, wpk_emg, bpart);
  const int span = B >> 4;                        // 128
  const int nblk = (NCE + NCI) * span + 1;        // 769
  fused_kernel<<<nblk, 256, 0, stream>>>(x_imu, x_emg, lens, wpk_imu, wpk_emg,
                                         b_proj, bpart, p_imu, p_emg, bias, B, T);
  combine_kernel<<<dim3(B, 2), 256, 0, stream>>>(bias, p_imu, p_emg, out, B);
}

// Round 15
// 82.859 us; speedup vs baseline: 2.2176x; 1.0016x over previous
//
#include <hip/hip_runtime.h>

#define NEWL 150
#define EMBD 64
#define NCOL 256
#define CIMU 48
#define CEMG 16

#define KIMU (NEWL * CIMU)  // 7200
#define KEMG (NEWL * CEMG)  // 2400
#define KSTI 225            // total k-steps (32-wide) imu
#define KSTE 75             // total k-steps emg
#define NCI 4               // imu s-chunks (19/19/19/18 groups)
#define NCE 2               // emg s-chunks (13/12 groups)

typedef __bf16 bf16x8_t __attribute__((ext_vector_type(8)));
typedef __bf16 bf16x4_t __attribute__((ext_vector_type(4)));
typedef float f32x4_t __attribute__((ext_vector_type(4)));

__device__ __forceinline__ f32x4_t mfma16(bf16x8_t a, bf16x8_t b, f32x4_t c) {
  return __builtin_amdgcn_mfma_f32_16x16x32_bf16(a, b, c, 0, 0, 0);
}

// ---------- K0: combined weights packed in MFMA B-fragment order + bias partials.
// W_pack[cb][ks][lane=h*16+(col&15)][u]  where k = ks*32 + h*8 + u
template <int C, int KST>
__device__ void wcomb_body(const float* __restrict__ wemb,
                           const float* __restrict__ wreg_src,
                           __bf16* __restrict__ wpk, int s, int j) {
  float wreg[EMBD];
#pragma unroll
  for (int e = 0; e < EMBD; ++e) wreg[e] = wreg_src[(size_t)e * NCOL];
  const int cb = j >> 4, lr = j & 15;
#pragma unroll
  for (int q = 0; q < C / 8; ++q) {
    const int kq = (s * C) / 8 + q;
    const int ks = kq >> 2, h = kq & 3;
    bf16x8_t tv;
#pragma unroll
    for (int u = 0; u < 8; ++u) {
      const float* we = wemb + (q * 8 + u) * EMBD;
      float acc = 0.f;
#pragma unroll
      for (int e = 0; e < EMBD; ++e) acc = fmaf(we[e], wreg[e], acc);
      tv[u] = (__bf16)acc;
    }
    *(bf16x8_t*)(wpk + (((size_t)cb * KST + ks) * 64 + h * 16 + lr) * 8) = tv;
  }
}

__global__ __launch_bounds__(256) void wcomb_kernel(
    const float* __restrict__ w_emb_imu, const float* __restrict__ w_emb_emg,
    const float* __restrict__ b_emb_imu, const float* __restrict__ b_emb_emg,
    const float* __restrict__ w_proj,
    __bf16* __restrict__ wpk_imu, __bf16* __restrict__ wpk_emg,
    float* __restrict__ bpart) {
  const int s = blockIdx.x;   // 0..149
  const int m = blockIdx.y;   // 0 = imu, 1 = emg
  const int j = threadIdx.x;  // output column 0..255
  const float* wp_base = w_proj + (size_t)s * EMBD * NCOL + j;
  const float* be = (m == 0) ? b_emb_imu : b_emb_emg;
  float bacc = 0.f;
#pragma unroll
  for (int e = 0; e < EMBD; ++e) bacc = fmaf(be[e], wp_base[(size_t)e * NCOL], bacc);
  bpart[((size_t)m * NEWL + s) * NCOL + j] = bacc;
  if (m == 0)
    wcomb_body<CIMU, KSTI>(w_emb_imu, wp_base, wpk_imu, s, j);
  else
    wcomb_body<CEMG, KSTE>(w_emb_emg, wp_base, wpk_emg, s, j);
}

// ---------- K1: fused ragged-interp + MFMA GEMM (+ bias-reduce tail block)
// R12 structure (distance-1, single static slot, 128-VGPR clamp) +
// XCD-contiguous rank swizzle: each XCD owns 96 consecutive ranks ->
// <=2 wpk chunk-slices per XCD (L2-resident, no thrash); nh-siblings
// rank-adjacent -> same XCD (gather L2 reuse preserved).
__global__ __launch_bounds__(256, 4) void fused_kernel(
    const float* __restrict__ x_imu, const float* __restrict__ x_emg,
    const int* __restrict__ lens,
    const __bf16* __restrict__ wpk_imu, const __bf16* __restrict__ wpk_emg,
    const float* __restrict__ b_proj, const float* __restrict__ bpart,
    float* __restrict__ p_imu, float* __restrict__ p_emg,
    float* __restrict__ bias, int B, int T) {
  const int bid = blockIdx.x;
  const int span = B >> 4;           // blocks per chunk (mts*2)
  const int nblk = (NCE + NCI) * span;  // 768 compute blocks
  if (bid == nblk) {  // bias tail block
    const int j = threadIdx.x;
#pragma unroll
    for (int m = 0; m < 2; ++m) {
      float acc = b_proj[j];
      for (int s = 0; s < NEWL; ++s) acc += bpart[((size_t)m * NEWL + s) * NCOL + j];
      bias[m * NCOL + j] = acc;
    }
    return;
  }

  __shared__ __bf16 lds[2][2][3][512];  // [buf][row-plane][ks][lane*8]

  const int tid = threadIdx.x;
  const int wv = tid >> 6, l = tid & 63;

  // XCD-contiguous rank: HW XCD = bid%8; give each XCD nblk/8 consecutive ranks.
  const int rank = (bid & 7) * (nblk >> 3) + (bid >> 3);
  const int cs = rank / span;
  const int r2 = rank - cs * span;
  const int mt = r2 >> 1;   // 0..63 (nh innermost: siblings rank-adjacent)
  const int nh = r2 & 1;
  const bool is_imu = cs >= NCE;
  const int c = is_imu ? cs - NCE : cs;

  // chunk geometry (group = 3 ksteps; imu: 2 s/group, emg: 6 s/group)
  int g0, NG;
  if (is_imu) { g0 = 19 * c; NG = (c < 3) ? 19 : 18; }
  else        { g0 = 13 * c; NG = c ? 12 : 13; }
  const int ks0 = 3 * g0;
  const int sb = is_imu ? 2 * g0 : 6 * g0;

  const __bf16* Wp = is_imu ? wpk_imu : wpk_emg;
  const int KST = is_imu ? KSTI : KSTE;
  float* P = is_imu ? (p_imu + (size_t)c * B * NCOL) : (p_emg + (size_t)c * B * NCOL);

  const size_t PS = (size_t)KST * 512;  // B fragment-plane stride (bf16)
  const __bf16* bg = Wp + ((size_t)(nh * 8 + wv * 2) * KST + ks0) * 512 + l * 8;

  // gather thread mappings
  const int q = tid & 3, sl = (tid >> 2) & 1, bli = tid >> 3;  // imu: 4 thr/(b,s)
  const int ble = tid / 6, se = tid - ble * 6;                 // emg: 1 thr/(b,s), tid<192
  const bool act = is_imu || (tid < 192);
  const int b_g = mt * 32 + (is_imu ? bli : (act ? ble : 0));
  int lenv = 1;
  float scale = 0.f;
  if (act) { lenv = lens[b_g]; scale = (float)lenv * (1.0f / 150.0f); }

  float gr[32];     // single gather slot (imu uses 24, emg 32)
  float wS;         // lerp weight
  bf16x8_t bB[6];   // single B slot (2 planes x 3 ksteps)
  f32x4_t acc00 = {0.f, 0.f, 0.f, 0.f}, acc01 = acc00, acc10 = acc00, acc11 = acc00;

// imu gather, quad-contiguous: lane q reads bytes [t*64+q*16) of both rows.
#define ISSUE_GI(g2) do {                                                       \
    const int s_ = sb + (g2) * 2 + sl;                                          \
    float src_ = fmaxf(((float)s_ + 0.5f) * scale - 0.5f, 0.0f);                \
    int i0_ = min((int)src_, lenv - 1);                                         \
    int i1_ = min(i0_ + 1, lenv - 1);                                           \
    wS = src_ - (float)i0_;                                                     \
    const float* r0_ = x_imu + ((size_t)b_g * T + i0_) * CIMU + q * 4;          \
    const float* r1_ = x_imu + ((size_t)b_g * T + i1_) * CIMU + q * 4;          \
    _Pragma("unroll")                                                           \
    for (int t = 0; t < 3; ++t) {                                               \
      float4 v_ = *(const float4*)(r0_ + t * 16);                               \
      gr[t * 4 + 0] = v_.x; gr[t * 4 + 1] = v_.y;                               \
      gr[t * 4 + 2] = v_.z; gr[t * 4 + 3] = v_.w;                               \
      float4 u_ = *(const float4*)(r1_ + t * 16);                               \
      gr[12 + t * 4 + 0] = u_.x; gr[12 + t * 4 + 1] = u_.y;                     \
      gr[12 + t * 4 + 2] = u_.z; gr[12 + t * 4 + 3] = u_.w;                     \
    }                                                                           \
  } while (0)

// in-lane lerp; all 4 quad threads write distinct bf16x4 pieces.
#define LERP_WI(BUF) do {                                                       \
    const float wg_ = wS, om_ = 1.0f - wg_;                                     \
    _Pragma("unroll")                                                           \
    for (int t = 0; t < 3; ++t) {                                               \
      bf16x4_t o_;                                                              \
      _Pragma("unroll")                                                         \
      for (int u = 0; u < 4; ++u)                                               \
        o_[u] = (__bf16)(gr[t * 4 + u] * om_ + gr[12 + t * 4 + u] * wg_);       \
      const int kq_ = sl * 6 + t * 2 + (q >> 1);                                \
      *(bf16x4_t*)(&lds[BUF][bli >> 4][kq_ >> 2]                                \
                       [((kq_ & 3) * 16 + (bli & 15)) * 8 + (q & 1) * 4]) = o_; \
    }                                                                           \
  } while (0)

#define ISSUE_GE(g2) do { if (act) {                                            \
    const int s_ = sb + (g2) * 6 + se;                                          \
    float src_ = fmaxf(((float)s_ + 0.5f) * scale - 0.5f, 0.0f);                \
    int i0_ = min((int)src_, lenv - 1);                                         \
    int i1_ = min(i0_ + 1, lenv - 1);                                           \
    wS = src_ - (float)i0_;                                                     \
    const float* p0_ = x_emg + ((size_t)b_g * T + i0_) * CEMG;                  \
    const float* p1_ = x_emg + ((size_t)b_g * T + i1_) * CEMG;                  \
    _Pragma("unroll")                                                           \
    for (int t = 0; t < 4; ++t) {                                               \
      float4 v_ = *(const float4*)(p0_ + t * 4);                                \
      gr[t * 4 + 0] = v_.x; gr[t * 4 + 1] = v_.y;                               \
      gr[t * 4 + 2] = v_.z; gr[t * 4 + 3] = v_.w;                               \
      float4 u_ = *(const float4*)(p1_ + t * 4);                                \
      gr[16 + t * 4 + 0] = u_.x; gr[16 + t * 4 + 1] = u_.y;                     \
      gr[16 + t * 4 + 2] = u_.z; gr[16 + t * 4 + 3] = u_.w;                     \
    }                                                                           \
  } } while (0)

#define LERP_WE(BUF) do { if (act) {                                            \
    const float wg_ = wS, om_ = 1.0f - wg_;                                     \
    _Pragma("unroll")                                                           \
    for (int t2 = 0; t2 < 2; ++t2) {                                            \
      bf16x8_t o_;                                                              \
      _Pragma("unroll")                                                         \
      for (int u = 0; u < 8; ++u)                                               \
        o_[u] = (__bf16)(gr[t2 * 8 + u] * om_ + gr[16 + t2 * 8 + u] * wg_);     \
      const int kq_ = se * 2 + t2;                                              \
      *(bf16x8_t*)(&lds[BUF][ble >> 4][kq_ >> 2]                                \
                       [((kq_ & 3) * 16 + (ble & 15)) * 8]) = o_;               \
    }                                                                           \
  } } while (0)

#define ISSUE_B(g1) do {                                                        \
    const __bf16* pb_ = bg + (size_t)((g1) * 3) * 512;                          \
    _Pragma("unroll")                                                           \
    for (int ks = 0; ks < 3; ++ks) {                                            \
      bB[ks * 2 + 0] = *(const bf16x8_t*)(pb_ + (size_t)ks * 512);              \
      bB[ks * 2 + 1] = *(const bf16x8_t*)(pb_ + PS + (size_t)ks * 512);         \
    }                                                                           \
  } while (0)

#define COMPUTE(Pp) do {                                                        \
    _Pragma("unroll")                                                           \
    for (int ks = 0; ks < 3; ++ks) {                                            \
      bf16x8_t a0_ = *(const bf16x8_t*)(&lds[Pp][0][ks][l * 8]);                \
      bf16x8_t a1_ = *(const bf16x8_t*)(&lds[Pp][1][ks][l * 8]);                \
      acc00 = mfma16(a0_, bB[ks * 2 + 0], acc00);                               \
      acc01 = mfma16(a0_, bB[ks * 2 + 1], acc01);                               \
      acc10 = mfma16(a1_, bB[ks * 2 + 0], acc10);                               \
      acc11 = mfma16(a1_, bB[ks * 2 + 1], acc11);                               \
    }                                                                           \
  } while (0)

  // prologue: stage group 0, load B0
  if (is_imu) { ISSUE_GI(0); LERP_WI(0); }
  else        { ISSUE_GE(0); LERP_WE(0); }
  ISSUE_B(0);
  __syncthreads();

  for (int p = 0; p < NG; ++p) {
    const int more = (p + 1 < NG);
    if (more) { if (is_imu) ISSUE_GI(p + 1); else ISSUE_GE(p + 1); }
    COMPUTE(p & 1);
    if (more) ISSUE_B(p + 1);
    if (more) { if (is_imu) LERP_WI((p + 1) & 1); else LERP_WE((p + 1) & 1); }
    __syncthreads();
  }

  // epilogue: C/D col = lane&15, row = (lane>>4)*4 + reg
  const int lh = l >> 4, lr = l & 15;
  float* Pb = P + (size_t)(mt * 32 + lh * 4) * NCOL + nh * 128 + wv * 32 + lr;
#pragma unroll
  for (int jj = 0; jj < 4; ++jj) {
    Pb[(size_t)jj * NCOL] = acc00[jj];
    Pb[(size_t)jj * NCOL + 16] = acc01[jj];
    Pb[(size_t)(16 + jj) * NCOL] = acc10[jj];
    Pb[(size_t)(16 + jj) * NCOL + 16] = acc11[jj];
  }
#undef ISSUE_GI
#undef LERP_WI
#undef ISSUE_GE
#undef LERP_WE
#undef ISSUE_B
#undef COMPUTE
}

// ---------- K2: sum split-K partials + bias -> d_out
__global__ __launch_bounds__(256) void combine_kernel(
    const float* __restrict__ bias, const float* __restrict__ p_imu,
    const float* __restrict__ p_emg, float* __restrict__ out, int B) {
  const int b = blockIdx.x, m = blockIdx.y, j = threadIdx.x;
  const size_t n = (size_t)B * NCOL;
  const size_t o = (size_t)b * NCOL + j;
  if (m == 0) {
    float v = bias[j];
#pragma unroll
    for (int c = 0; c < NCI; ++c) v += p_imu[c * n + o];
    out[o] = v;
  } else {
    out[n + o] = bias[NCOL + j] + p_emg[o] + p_emg[n + o];
  }
}

extern "C" void kernel_launch(void* const* d_in, const int* in_sizes, int n_in,
                              void* d_out, int out_size, void* d_ws, size_t ws_size,
                              hipStream_t stream) {
  const float* x_imu     = (const float*)d_in[0];
  const float* x_emg     = (const float*)d_in[1];
  const int*   lens      = (const int*)d_in[2];
  const float* w_emb_imu = (const float*)d_in[3];
  const float* b_emb_imu = (const float*)d_in[4];
  const float* w_emb_emg = (const float*)d_in[5];
  const float* b_emb_emg = (const float*)d_in[6];
  const float* w_proj    = (const float*)d_in[7];
  const float* b_proj    = (const float*)d_in[8];
  float* out = (float*)d_out;

  const int B = in_sizes[2];
  const int T = in_sizes[0] / (B * CIMU);

  char* ws = (char*)d_ws;
  __bf16* wpk_imu = (__bf16*)ws;  ws += (size_t)NCOL * KIMU * 2;
  __bf16* wpk_emg = (__bf16*)ws;  ws += (size_t)NCOL * KEMG * 2;
  float*  bias    = (float*)ws;   ws += 2 * NCOL * 4;
  float*  bpart   = (float*)ws;   ws += (size_t)2 * NEWL * NCOL * 4;
  float*  p_imu   = (float*)ws;   ws += (size_t)NCI * B * NCOL * 4;
  float*  p_emg   = (float*)ws;   ws += (size_t)NCE * B * NCOL * 4;

  wcomb_kernel<<<dim3(NEWL, 2), 256, 0, stream>>>(
      w_emb_imu, w_emb_emg, b_emb_imu, b_emb_emg, w_proj, wpk_imu, wpk_emg, bpart);
  const int span = B >> 4;                        // 128
  const int nblk = (NCE + NCI) * span + 1;        // 769
  fused_kernel<<<nblk, 256, 0, stream>>>(x_imu, x_emg, lens, wpk_imu, wpk_emg,
                                         b_proj, bpart, p_imu, p_emg, bias, B, T);
  combine_kernel<<<dim3(B, 2), 256, 0, stream>>>(bias, p_imu, p_emg, out, B);
}

// Round 16
// 81.032 us; speedup vs baseline: 2.2676x; 1.0226x over previous
//
#include <hip/hip_runtime.h>

#define NEWL 150
#define EMBD 64
#define NCOL 256
#define CIMU 48
#define CEMG 16

#define KIMU (NEWL * CIMU)  // 7200
#define KEMG (NEWL * CEMG)  // 2400
#define KSTI 225            // total k-steps (32-wide) imu
#define KSTE 75             // total k-steps emg
#define NCI 4               // imu s-chunks (19/19/19/18 groups)
#define NCE 2               // emg s-chunks (13/12 groups)

typedef __bf16 bf16x8_t __attribute__((ext_vector_type(8)));
typedef __bf16 bf16x4_t __attribute__((ext_vector_type(4)));
typedef float f32x4_t __attribute__((ext_vector_type(4)));

__device__ __forceinline__ f32x4_t mfma16(bf16x8_t a, bf16x8_t b, f32x4_t c) {
  return __builtin_amdgcn_mfma_f32_16x16x32_bf16(a, b, c, 0, 0, 0);
}

// ---------- K0: combined weights packed in MFMA B-fragment order + bias partials.
// W_pack[cb][ks][lane=h*16+(col&15)][u]  where k = ks*32 + h*8 + u
template <int C, int KST>
__device__ void wcomb_body(const float* __restrict__ wemb,
                           const float* __restrict__ wreg_src,
                           __bf16* __restrict__ wpk, int s, int j) {
  float wreg[EMBD];
#pragma unroll
  for (int e = 0; e < EMBD; ++e) wreg[e] = wreg_src[(size_t)e * NCOL];
  const int cb = j >> 4, lr = j & 15;
#pragma unroll
  for (int q = 0; q < C / 8; ++q) {
    const int kq = (s * C) / 8 + q;
    const int ks = kq >> 2, h = kq & 3;
    bf16x8_t tv;
#pragma unroll
    for (int u = 0; u < 8; ++u) {
      const float* we = wemb + (q * 8 + u) * EMBD;
      float acc = 0.f;
#pragma unroll
      for (int e = 0; e < EMBD; ++e) acc = fmaf(we[e], wreg[e], acc);
      tv[u] = (__bf16)acc;
    }
    *(bf16x8_t*)(wpk + (((size_t)cb * KST + ks) * 64 + h * 16 + lr) * 8) = tv;
  }
}

__global__ __launch_bounds__(256) void wcomb_kernel(
    const float* __restrict__ w_emb_imu, const float* __restrict__ w_emb_emg,
    const float* __restrict__ b_emb_imu, const float* __restrict__ b_emb_emg,
    const float* __restrict__ w_proj,
    __bf16* __restrict__ wpk_imu, __bf16* __restrict__ wpk_emg,
    float* __restrict__ bpart) {
  const int s = blockIdx.x;   // 0..149
  const int m = blockIdx.y;   // 0 = imu, 1 = emg
  const int j = threadIdx.x;  // output column 0..255
  const float* wp_base = w_proj + (size_t)s * EMBD * NCOL + j;
  const float* be = (m == 0) ? b_emb_imu : b_emb_emg;
  float bacc = 0.f;
#pragma unroll
  for (int e = 0; e < EMBD; ++e) bacc = fmaf(be[e], wp_base[(size_t)e * NCOL], bacc);
  bpart[((size_t)m * NEWL + s) * NCOL + j] = bacc;
  if (m == 0)
    wcomb_body<CIMU, KSTI>(w_emb_imu, wp_base, wpk_imu, s, j);
  else
    wcomb_body<CEMG, KSTE>(w_emb_emg, wp_base, wpk_emg, s, j);
}

// ---------- K1: fused ragged-interp + MFMA GEMM, 512-thread blocks.
// One block = (32-row m-tile, FULL 256 cols, s-chunk); 8 waves = 8 col-planes.
// Each gather row fetched exactly once (no nh-sibling duplication).
// Distance-1 pipeline, static slots, VGPR<=128 via launch_bounds(512,2).
__global__ __launch_bounds__(512, 2) void fused_kernel(
    const float* __restrict__ x_imu, const float* __restrict__ x_emg,
    const int* __restrict__ lens,
    const __bf16* __restrict__ wpk_imu, const __bf16* __restrict__ wpk_emg,
    const float* __restrict__ b_proj, const float* __restrict__ bpart,
    float* __restrict__ p_imu, float* __restrict__ p_emg,
    float* __restrict__ bias, int B, int T) {
  const int bid = blockIdx.x;
  const int span = B >> 5;               // 64 m-tiles per chunk
  const int nblk = (NCE + NCI) * span;   // 384 compute blocks
  if (bid == nblk) {  // bias tail block
    const int j = threadIdx.x;
    if (j < NCOL) {
#pragma unroll
      for (int m = 0; m < 2; ++m) {
        float acc = b_proj[j];
        for (int s = 0; s < NEWL; ++s)
          acc += bpart[((size_t)m * NEWL + s) * NCOL + j];
        bias[m * NCOL + j] = acc;
      }
    }
    return;
  }

  __shared__ __bf16 lds[2][2][3][512];  // [buf][row-plane][ks][lane*8]

  const int tid = threadIdx.x;
  const int wv = tid >> 6, l = tid & 63;

  const int cs = bid / span;
  const int mt = bid - cs * span;
  const bool is_imu = cs >= NCE;
  const int c = is_imu ? cs - NCE : cs;

  // chunk geometry (group = 3 ksteps; imu: 2 s/group, emg: 6 s/group)
  int g0, NG;
  if (is_imu) { g0 = 19 * c; NG = (c < 3) ? 19 : 18; }
  else        { g0 = 13 * c; NG = c ? 12 : 13; }
  const int ks0 = 3 * g0;
  const int sb = is_imu ? 2 * g0 : 6 * g0;

  const __bf16* Wp = is_imu ? wpk_imu : wpk_emg;
  const int KST = is_imu ? KSTI : KSTE;
  float* P = is_imu ? (p_imu + (size_t)c * B * NCOL) : (p_emg + (size_t)c * B * NCOL);

  const size_t PS = (size_t)KST * 512;  // B fragment-plane stride (bf16)
  // wave wv owns col-planes wv*2, wv*2+1 (16 cols each -> 32 cols/wave)
  const __bf16* bg = Wp + ((size_t)(wv * 2) * KST + ks0) * 512 + l * 8;

  // gather thread mappings
  // imu: 8 thr/(b,s): pid=tid>>3 (b4=pid&31, sl=pid>>5), row=(tid>>2)&1, q=tid&3
  const int q = tid & 3, rowb = (tid >> 2) & 1;
  const int pid = tid >> 3, b4 = pid & 31, sl = pid >> 5;
  // emg: 2 thr/(b,s): pid_e=tid>>1 (ble=pid_e/6, se=pid_e%6), row=tid&1; tid<384
  const int pid_e = tid >> 1;
  const int ble = pid_e / 6, se = pid_e - ble * 6, rowe = tid & 1;
  const bool act = is_imu || (tid < 384);
  const int b_g = mt * 32 + (is_imu ? b4 : (act ? ble : 0));
  int lenv = 1;
  float scale = 0.f;
  if (act) { lenv = lens[b_g]; scale = (float)lenv * (1.0f / 150.0f); }

  float gr[16];     // imu uses 12 (one row quarter x3), emg 16 (one row)
  float wS;         // lerp weight
  bf16x8_t bB[6];   // single B slot (2 planes x 3 ksteps)
  f32x4_t acc00 = {0.f, 0.f, 0.f, 0.f}, acc01 = acc00, acc10 = acc00, acc11 = acc00;

// imu gather: thread reads ONE row (i0 or i1 by rowb), quarter q: 3x float4.
#define ISSUE_GI(g2) do {                                                       \
    const int s_ = sb + (g2) * 2 + sl;                                          \
    float src_ = fmaxf(((float)s_ + 0.5f) * scale - 0.5f, 0.0f);                \
    int i0_ = min((int)src_, lenv - 1);                                         \
    int i1_ = min(i0_ + 1, lenv - 1);                                           \
    wS = src_ - (float)i0_;                                                     \
    const float* r_ =                                                           \
        x_imu + ((size_t)b_g * T + (rowb ? i1_ : i0_)) * CIMU + q * 4;          \
    _Pragma("unroll")                                                           \
    for (int t = 0; t < 3; ++t) {                                               \
      float4 v_ = *(const float4*)(r_ + t * 16);                                \
      gr[t * 4 + 0] = v_.x; gr[t * 4 + 1] = v_.y;                               \
      gr[t * 4 + 2] = v_.z; gr[t * 4 + 3] = v_.w;                               \
    }                                                                           \
  } while (0)

// lerp: partner (other row) is lane^4; row0 threads compute+write LDS.
#define LERP_WI(BUF) do {                                                       \
    const float wg_ = wS, om_ = 1.0f - wg_;                                     \
    _Pragma("unroll")                                                           \
    for (int t = 0; t < 3; ++t) {                                               \
      float p0_ = __shfl_xor(gr[t * 4 + 0], 4);                                 \
      float p1_ = __shfl_xor(gr[t * 4 + 1], 4);                                 \
      float p2_ = __shfl_xor(gr[t * 4 + 2], 4);                                 \
      float p3_ = __shfl_xor(gr[t * 4 + 3], 4);                                 \
      if (rowb == 0) {                                                          \
        bf16x4_t o_;                                                            \
        o_[0] = (__bf16)(gr[t * 4 + 0] * om_ + p0_ * wg_);                      \
        o_[1] = (__bf16)(gr[t * 4 + 1] * om_ + p1_ * wg_);                      \
        o_[2] = (__bf16)(gr[t * 4 + 2] * om_ + p2_ * wg_);                      \
        o_[3] = (__bf16)(gr[t * 4 + 3] * om_ + p3_ * wg_);                      \
        const int kq_ = sl * 6 + t * 2 + (q >> 1);                              \
        *(bf16x4_t*)(&lds[BUF][b4 >> 4][kq_ >> 2]                               \
                         [((kq_ & 3) * 16 + (b4 & 15)) * 8 + (q & 1) * 4]) = o_;\
      }                                                                         \
    }                                                                           \
  } while (0)

// emg gather: thread reads ONE row (i0 or i1 by rowe): 4x float4.
#define ISSUE_GE(g2) do { if (act) {                                            \
    const int s_ = sb + (g2) * 6 + se;                                          \
    float src_ = fmaxf(((float)s_ + 0.5f) * scale - 0.5f, 0.0f);                \
    int i0_ = min((int)src_, lenv - 1);                                         \
    int i1_ = min(i0_ + 1, lenv - 1);                                           \
    wS = src_ - (float)i0_;                                                     \
    const float* r_ = x_emg + ((size_t)b_g * T + (rowe ? i1_ : i0_)) * CEMG;    \
    _Pragma("unroll")                                                           \
    for (int t = 0; t < 4; ++t) {                                               \
      float4 v_ = *(const float4*)(r_ + t * 4);                                 \
      gr[t * 4 + 0] = v_.x; gr[t * 4 + 1] = v_.y;                               \
      gr[t * 4 + 2] = v_.z; gr[t * 4 + 3] = v_.w;                               \
    }                                                                           \
  } } while (0)

// emg lerp: partner lane^1; row0 thread writes 2 bf16x8.
#define LERP_WE(BUF) do { if (act) {                                            \
    const float wg_ = wS, om_ = 1.0f - wg_;                                     \
    _Pragma("unroll")                                                           \
    for (int t2 = 0; t2 < 2; ++t2) {                                            \
      float pv_[8];                                                             \
      _Pragma("unroll")                                                         \
      for (int u = 0; u < 8; ++u) pv_[u] = __shfl_xor(gr[t2 * 8 + u], 1);       \
      if (rowe == 0) {                                                          \
        bf16x8_t o_;                                                            \
        _Pragma("unroll")                                                       \
        for (int u = 0; u < 8; ++u)                                             \
          o_[u] = (__bf16)(gr[t2 * 8 + u] * om_ + pv_[u] * wg_);                \
        const int kq_ = se * 2 + t2;                                            \
        *(bf16x8_t*)(&lds[BUF][ble >> 4][kq_ >> 2]                              \
                         [((kq_ & 3) * 16 + (ble & 15)) * 8]) = o_;             \
      }                                                                         \
    }                                                                           \
  } } while (0)

#define ISSUE_B(g1) do {                                                        \
    const __bf16* pb_ = bg + (size_t)((g1) * 3) * 512;                          \
    _Pragma("unroll")                                                           \
    for (int ks = 0; ks < 3; ++ks) {                                            \
      bB[ks * 2 + 0] = *(const bf16x8_t*)(pb_ + (size_t)ks * 512);              \
      bB[ks * 2 + 1] = *(const bf16x8_t*)(pb_ + PS + (size_t)ks * 512);         \
    }                                                                           \
  } while (0)

#define COMPUTE(Pp) do {                                                        \
    _Pragma("unroll")                                                           \
    for (int ks = 0; ks < 3; ++ks) {                                            \
      bf16x8_t a0_ = *(const bf16x8_t*)(&lds[Pp][0][ks][l * 8]);                \
      bf16x8_t a1_ = *(const bf16x8_t*)(&lds[Pp][1][ks][l * 8]);                \
      acc00 = mfma16(a0_, bB[ks * 2 + 0], acc00);                               \
      acc01 = mfma16(a0_, bB[ks * 2 + 1], acc01);                               \
      acc10 = mfma16(a1_, bB[ks * 2 + 0], acc10);                               \
      acc11 = mfma16(a1_, bB[ks * 2 + 1], acc11);                               \
    }                                                                           \
  } while (0)

  // prologue: stage group 0, load B0
  if (is_imu) { ISSUE_GI(0); LERP_WI(0); }
  else        { ISSUE_GE(0); LERP_WE(0); }
  ISSUE_B(0);
  __syncthreads();

  for (int p = 0; p < NG; ++p) {
    const int more = (p + 1 < NG);
    if (more) { if (is_imu) ISSUE_GI(p + 1); else ISSUE_GE(p + 1); }
    COMPUTE(p & 1);
    if (more) ISSUE_B(p + 1);
    if (more) { if (is_imu) LERP_WI((p + 1) & 1); else LERP_WE((p + 1) & 1); }
    __syncthreads();
  }

  // epilogue: C/D col = lane&15, row = (lane>>4)*4 + reg
  const int lh = l >> 4, lr = l & 15;
  float* Pb = P + (size_t)(mt * 32 + lh * 4) * NCOL + wv * 32 + lr;
#pragma unroll
  for (int jj = 0; jj < 4; ++jj) {
    Pb[(size_t)jj * NCOL] = acc00[jj];
    Pb[(size_t)jj * NCOL + 16] = acc01[jj];
    Pb[(size_t)(16 + jj) * NCOL] = acc10[jj];
    Pb[(size_t)(16 + jj) * NCOL + 16] = acc11[jj];
  }
#undef ISSUE_GI
#undef LERP_WI
#undef ISSUE_GE
#undef LERP_WE
#undef ISSUE_B
#undef COMPUTE
}

// ---------- K2: sum split-K partials + bias -> d_out
__global__ __launch_bounds__(256) void combine_kernel(
    const float* __restrict__ bias, const float* __restrict__ p_imu,
    const float* __restrict__ p_emg, float* __restrict__ out, int B) {
  const int b = blockIdx.x, m = blockIdx.y, j = threadIdx.x;
  const size_t n = (size_t)B * NCOL;
  const size_t o = (size_t)b * NCOL + j;
  if (m == 0) {
    float v = bias[j];
#pragma unroll
    for (int c = 0; c < NCI; ++c) v += p_imu[c * n + o];
    out[o] = v;
  } else {
    out[n + o] = bias[NCOL + j] + p_emg[o] + p_emg[n + o];
  }
}

extern "C" void kernel_launch(void* const* d_in, const int* in_sizes, int n_in,
                              void* d_out, int out_size, void* d_ws, size_t ws_size,
                              hipStream_t stream) {
  const float* x_imu     = (const float*)d_in[0];
  const float* x_emg     = (const float*)d_in[1];
  const int*   lens      = (const int*)d_in[2];
  const float* w_emb_imu = (const float*)d_in[3];
  const float* b_emb_imu = (const float*)d_in[4];
  const float* w_emb_emg = (const float*)d_in[5];
  const float* b_emb_emg = (const float*)d_in[6];
  const float* w_proj    = (const float*)d_in[7];
  const float* b_proj    = (const float*)d_in[8];
  float* out = (float*)d_out;

  const int B = in_sizes[2];
  const int T = in_sizes[0] / (B * CIMU);

  char* ws = (char*)d_ws;
  __bf16* wpk_imu = (__bf16*)ws;  ws += (size_t)NCOL * KIMU * 2;
  __bf16* wpk_emg = (__bf16*)ws;  ws += (size_t)NCOL * KEMG * 2;
  float*  bias    = (float*)ws;   ws += 2 * NCOL * 4;
  float*  bpart   = (float*)ws;   ws += (size_t)2 * NEWL * NCOL * 4;
  float*  p_imu   = (float*)ws;   ws += (size_t)NCI * B * NCOL * 4;
  float*  p_emg   = (float*)ws;   ws += (size_t)NCE * B * NCOL * 4;

  wcomb_kernel<<<dim3(NEWL, 2), 256, 0, stream>>>(
      w_emb_imu, w_emb_emg, b_emb_imu, b_emb_emg, w_proj, wpk_imu, wpk_emg, bpart);
  const int span = B >> 5;                        // 64
  const int nblk = (NCE + NCI) * span + 1;        // 385
  fused_kernel<<<nblk, 512, 0, stream>>>(x_imu, x_emg, lens, wpk_imu, wpk_emg,
                                         b_proj, bpart, p_imu, p_emg, bias, B, T);
  combine_kernel<<<dim3(B, 2), 256, 0, stream>>>(bias, p_imu, p_emg, out, B);
}